// Round 1
// baseline (531.060 us; speedup 1.0000x reference)
//
#include <hip/hip_runtime.h>
#include <hip/hip_bf16.h>
#include <math.h>

#define Bt 8
#define Ct 64
#define Ht 128
#define Wt 128
#define Ot 64
#define HWt (Ht*Wt)
#define K2 9
#define CK 576   // C*K2

// ---------------- prep: weight reshapes ----------------
// wPrep[cp*28 + ch] : cp = c*9+pos, ch in [0,18) from w_off, [18,27) from w_mask, 27 = pad
// wT[ck*64 + o]     : ck = c*9+k, transposed w_dcn
__global__ __launch_bounds__(256) void prep_kernel(
    const float* __restrict__ w_off, const float* __restrict__ w_mask,
    const float* __restrict__ w_dcn, float* __restrict__ wPrep, float* __restrict__ wT)
{
    int i = blockIdx.x * 256 + threadIdx.x;
    const int NP = CK * 28;       // 16128
    const int NT = CK * Ot;       // 36864
    if (i < NP) {
        int cp = i / 28;
        int ch = i - cp * 28;
        float v = 0.f;
        if (ch < 18)       v = w_off[ch * CK + cp];
        else if (ch < 27)  v = w_mask[(ch - 18) * CK + cp];
        wPrep[i] = v;
    } else if (i < NP + NT) {
        int j = i - NP;
        int ck = j >> 6;
        int o  = j & 63;
        wT[j] = w_dcn[o * CK + ck];
    }
}

// ---------------- offset/mask conv ----------------
// one thread per pixel, 27 output channels; dy/dx/mask written as [b][k][H][W]
__global__ __launch_bounds__(256) void offmask_kernel(
    const float* __restrict__ x, const float* __restrict__ wPrep,
    const float* __restrict__ b_off, const float* __restrict__ b_mask,
    float* __restrict__ dyp, float* __restrict__ dxp, float* __restrict__ mkp)
{
    int p = blockIdx.x * 256 + threadIdx.x;       // 0 .. B*H*W
    int b  = p >> 14;
    int y  = (p >> 7) & 127;
    int xx = p & 127;

    float acc[27];
#pragma unroll
    for (int i = 0; i < 18; ++i) acc[i] = b_off[i];
#pragma unroll
    for (int j = 0; j < 9; ++j)  acc[18 + j] = b_mask[j];

    const float* xb = x + ((size_t)b << 20);      // b*64*16384

#pragma unroll
    for (int pos = 0; pos < 9; ++pos) {
        int di = pos / 3, dj = pos - (pos / 3) * 3;
        int yy  = y + di - 1;
        int xx2 = xx + dj - 1;
        bool valid = ((unsigned)yy < 128u) && ((unsigned)xx2 < 128u);
        const float* xp = xb + yy * 128 + xx2;
        const float* wp = wPrep + pos * 28;
        for (int c = 0; c < 64; ++c) {
            float xv = valid ? xp[c * HWt] : 0.f;
            const float* wrow = wp + c * 9 * 28;
#pragma unroll
            for (int ch = 0; ch < 27; ++ch)
                acc[ch] = fmaf(xv, wrow[ch], acc[ch]);
        }
    }

    int base = (y << 7) + xx;
#pragma unroll
    for (int k = 0; k < 9; ++k) {
        int idx = ((b * 9 + k) << 14) + base;
        dyp[idx] = acc[2 * k];
        dxp[idx] = acc[2 * k + 1];
        mkp[idx] = 1.f / (1.f + __expf(-acc[18 + k]));
    }
}

// ---------------- main: sample + contract ----------------
// block = 256 threads, tile = 64 pixels (half a row), K blocked by 72 (8 c x 9 k)
__global__ __launch_bounds__(256) void dcn_main_kernel(
    const float* __restrict__ x,
    const float* __restrict__ dyp, const float* __restrict__ dxp, const float* __restrict__ mkp,
    const float* __restrict__ wT, const float* __restrict__ b_dcn,
    float* __restrict__ out)
{
    __shared__ float sL[72][64];
    __shared__ float wLs[72][64];
    __shared__ float dyL[9][64];
    __shared__ float dxL[9][64];
    __shared__ float mkL[9][64];

    int t  = threadIdx.x;
    int p0 = blockIdx.x * 64;
    int b  = p0 >> 14;
    int rem = p0 & 16383;
    int y  = rem >> 7;
    int x0 = rem & 127;          // 0 or 64

    // stage dy/dx/mask for the 64-pixel row segment
    for (int i = t; i < 3 * 576; i += 256) {
        int arr = i / 576;
        int r   = i - arr * 576;
        int k   = r >> 6;
        int px  = r & 63;
        const float* src = (arr == 0) ? dyp : (arr == 1 ? dxp : mkp);
        float v = src[((b * 9 + k) << 14) + (y << 7) + x0 + px];
        float* dst = (arr == 0) ? &dyL[0][0] : (arr == 1 ? &dxL[0][0] : &mkL[0][0]);
        dst[(k << 6) + px] = v;
    }
    __syncthreads();

    int px_l = t & 63;
    int sub  = t >> 6;           // 0..3 -> handles 2 channels of the 8-chunk
    int ti   = t & 15;           // pixel group (4 px)
    int tj   = t >> 4;           // o group (4 o)
    int xc0  = x0 + px_l;
    const float* xb = x + ((size_t)b << 20);

    float facc[4][4];
#pragma unroll
    for (int a = 0; a < 4; ++a)
#pragma unroll
        for (int bb = 0; bb < 4; ++bb) facc[a][bb] = 0.f;

    for (int cb = 0; cb < 8; ++cb) {
        // stage wT chunk [cb*72 .. cb*72+72) x [64]
        for (int j = 0; j < 18; ++j) {
            int idx = j * 256 + t;
            int ckl = idx >> 6;
            int o   = idx & 63;
            wLs[ckl][o] = wT[((cb * 72 + ckl) << 6) + o];
        }
        // sample 2 channels x 9 taps per thread
        int c0 = cb * 8 + sub * 2;
#pragma unroll
        for (int k = 0; k < 9; ++k) {
            int ki = k / 3, kj = k - (k / 3) * 3;
            float dyv = dyL[k][px_l];
            float dxv = dxL[k][px_l];
            float mkv = mkL[k][px_l];
            float py  = (float)(y - 1 + ki) + dyv;
            float pxf = (float)(xc0 - 1 + kj) + dxv;
            float y0f = floorf(py), x0f = floorf(pxf);
            float wy1 = py - y0f, wy0 = 1.f - wy1;
            float wx1 = pxf - x0f, wx0 = 1.f - wx1;
            bool vy0 = (y0f >= 0.f) && (y0f <= 127.f);
            bool vy1 = (y0f + 1.f >= 0.f) && (y0f + 1.f <= 127.f);
            bool vx0 = (x0f >= 0.f) && (x0f <= 127.f);
            bool vx1 = (x0f + 1.f >= 0.f) && (x0f + 1.f <= 127.f);
            int yi0 = (int)y0f, xi0 = (int)x0f;
            int y0c = min(max(yi0, 0), 127);
            int y1c = min(max(yi0 + 1, 0), 127);
            int x0c = min(max(xi0, 0), 127);
            int x1c = min(max(xi0 + 1, 0), 127);
            int a00 = (y0c << 7) + x0c;
            int a01 = (y0c << 7) + x1c;
            int a10 = (y1c << 7) + x0c;
            int a11 = (y1c << 7) + x1c;
#pragma unroll
            for (int cc = 0; cc < 2; ++cc) {
                const float* img = xb + (c0 + cc) * HWt;
                float v00 = (vy0 && vx0) ? img[a00] : 0.f;
                float v01 = (vy0 && vx1) ? img[a01] : 0.f;
                float v10 = (vy1 && vx0) ? img[a10] : 0.f;
                float v11 = (vy1 && vx1) ? img[a11] : 0.f;
                float val = wy0 * (wx0 * v00 + wx1 * v01) + wy1 * (wx0 * v10 + wx1 * v11);
                sL[(sub * 2 + cc) * 9 + k][px_l] = val * mkv;
            }
        }
        __syncthreads();

        // register-tiled 4x4 fp32 GEMM over this 72-slice
#pragma unroll 8
        for (int ckl = 0; ckl < 72; ++ckl) {
            float4 sv = *(const float4*)&sL[ckl][ti * 4];
            float4 wv = *(const float4*)&wLs[ckl][tj * 4];
            facc[0][0] = fmaf(wv.x, sv.x, facc[0][0]);
            facc[0][1] = fmaf(wv.x, sv.y, facc[0][1]);
            facc[0][2] = fmaf(wv.x, sv.z, facc[0][2]);
            facc[0][3] = fmaf(wv.x, sv.w, facc[0][3]);
            facc[1][0] = fmaf(wv.y, sv.x, facc[1][0]);
            facc[1][1] = fmaf(wv.y, sv.y, facc[1][1]);
            facc[1][2] = fmaf(wv.y, sv.z, facc[1][2]);
            facc[1][3] = fmaf(wv.y, sv.w, facc[1][3]);
            facc[2][0] = fmaf(wv.z, sv.x, facc[2][0]);
            facc[2][1] = fmaf(wv.z, sv.y, facc[2][1]);
            facc[2][2] = fmaf(wv.z, sv.z, facc[2][2]);
            facc[2][3] = fmaf(wv.z, sv.w, facc[2][3]);
            facc[3][0] = fmaf(wv.w, sv.x, facc[3][0]);
            facc[3][1] = fmaf(wv.w, sv.y, facc[3][1]);
            facc[3][2] = fmaf(wv.w, sv.z, facc[3][2]);
            facc[3][3] = fmaf(wv.w, sv.w, facc[3][3]);
        }
        __syncthreads();
    }

    // epilogue: add bias, float4 stores
#pragma unroll
    for (int a = 0; a < 4; ++a) {
        int o = tj * 4 + a;
        float bias = b_dcn[o];
        float4 r;
        r.x = facc[a][0] + bias;
        r.y = facc[a][1] + bias;
        r.z = facc[a][2] + bias;
        r.w = facc[a][3] + bias;
        *(float4*)&out[(size_t)(((b * 64 + o) << 14) + (y << 7) + x0 + ti * 4)] = r;
    }
}

extern "C" void kernel_launch(void* const* d_in, const int* in_sizes, int n_in,
                              void* d_out, int out_size, void* d_ws, size_t ws_size,
                              hipStream_t stream) {
    const float* x      = (const float*)d_in[0];
    const float* w_off  = (const float*)d_in[1];
    const float* b_off  = (const float*)d_in[2];
    const float* w_mask = (const float*)d_in[3];
    const float* b_mask = (const float*)d_in[4];
    const float* w_dcn  = (const float*)d_in[5];
    const float* b_dcn  = (const float*)d_in[6];
    float* out = (float*)d_out;

    // workspace layout (floats)
    const size_t N1 = (size_t)Bt * 9 * HWt;   // 1179648
    float* ws  = (float*)d_ws;
    float* dyp = ws;
    float* dxp = ws + N1;
    float* mkp = ws + 2 * N1;
    float* wT  = ws + 3 * N1;                 // 36864
    float* wPrep = wT + (size_t)CK * Ot;      // 16128

    {
        int total = CK * 28 + CK * Ot;
        int blocks = (total + 255) / 256;
        hipLaunchKernelGGL(prep_kernel, dim3(blocks), dim3(256), 0, stream,
                           w_off, w_mask, w_dcn, wPrep, wT);
    }
    {
        int blocks = (Bt * HWt) / 256;        // 512
        hipLaunchKernelGGL(offmask_kernel, dim3(blocks), dim3(256), 0, stream,
                           x, wPrep, b_off, b_mask, dyp, dxp, mkp);
    }
    {
        int blocks = (Bt * HWt) / 64;         // 2048
        hipLaunchKernelGGL(dcn_main_kernel, dim3(blocks), dim3(256), 0, stream,
                           x, dyp, dxp, mkp, wT, b_dcn, out);
    }
}

// Round 3
// 205.061 us; speedup vs baseline: 2.5898x; 2.5898x over previous
//
#include <hip/hip_runtime.h>
#include <hip/hip_bf16.h>
#include <math.h>

#define Bt 8
#define Ct 64
#define Ht 128
#define Wt 128
#define Ot 64
#define HWt (Ht*Wt)

typedef __bf16 bf16x8 __attribute__((ext_vector_type(8)));
typedef float  f32x4  __attribute__((ext_vector_type(4)));

// fp32 -> bf16 bits, round-to-nearest-even, in pure integer ops
__device__ __forceinline__ uint f2bf_bits(float v) {
    uint u = __float_as_uint(v);
    uint lsb = (u >> 16) & 1u;
    return (u + 0x7fffu + lsb) >> 16;
}
__device__ __forceinline__ ushort f2bf(float v) {
    return (ushort)f2bf_bits(v);
}

// ---------------- prep ----------------
// blocks 0..1023: transpose x NCHW fp32 -> xTb NHWC bf16  [b][y][x][c]
// blocks 1024.. : weight reshapes
//   wOffB[(k*32+ch)*64+c] = ch<18 ? w_off[ch][c][k] : ch<27 ? w_mask[ch-18][c][k] : 0
//   wMainB[(k*64+o)*64+c] = w_dcn[o][c][k]
__global__ __launch_bounds__(256) void prep_kernel(
    const float* __restrict__ x, const float* __restrict__ w_off,
    const float* __restrict__ w_mask, const float* __restrict__ w_dcn,
    ushort* __restrict__ xTb, ushort* __restrict__ wOffB, ushort* __restrict__ wMainB)
{
    int blk = blockIdx.x;
    int t = threadIdx.x;
    if (blk < 1024) {
        __shared__ float L[64][128];
        int b = blk >> 7, y = blk & 127;
        const float* xb = x + (size_t)b * 1048576 + y * 128;
        int xx = t & 127, ch2 = t >> 7;
#pragma unroll
        for (int cc = 0; cc < 32; ++cc) {
            int c = cc * 2 + ch2;
            L[c][xx] = xb[(size_t)c * HWt + xx];
        }
        __syncthreads();
        int px = t >> 1, half = (t & 1) * 32;
        union { ushort u[32]; uint4 q[4]; } pk;
#pragma unroll
        for (int i = 0; i < 32; ++i) pk.u[i] = f2bf(L[half + i][px]);
        uint4* dst = (uint4*)(xTb + ((size_t)blk * 128 + px) * 64 + half);
        dst[0] = pk.q[0]; dst[1] = pk.q[1]; dst[2] = pk.q[2]; dst[3] = pk.q[3];
    } else {
        int i = (blk - 1024) * 256 + t;
        if (i < 9 * 32 * 64) {
            int c = i & 63, ch = (i >> 6) & 31, k = i >> 11;
            float v = 0.f;
            if (ch < 18)      v = w_off[(ch * 64 + c) * 9 + k];
            else if (ch < 27) v = w_mask[((ch - 18) * 64 + c) * 9 + k];
            wOffB[i] = f2bf(v);
        } else {
            int j = i - 18432;
            if (j < 9 * 64 * 64) {
                int c = j & 63, o = (j >> 6) & 63, k = j >> 12;
                wMainB[j] = f2bf(w_dcn[(o * 64 + c) * 9 + k]);
            }
        }
    }
}

// ---------------- offset/mask conv via MFMA ----------------
// block: 64 px (half row), M=64 (4 waves x 16), N=32, K=576 (9 taps x 64c)
__global__ __launch_bounds__(256) void offmask_kernel(
    const ushort* __restrict__ xTb, const ushort* __restrict__ wOffB,
    const float* __restrict__ b_off, const float* __restrict__ b_mask,
    float* __restrict__ dyp, float* __restrict__ dxp, float* __restrict__ mkp)
{
    __shared__ ushort sA[64][72];
    __shared__ ushort wL[32][72];
    int t = threadIdx.x;
    int p0 = blockIdx.x * 64;
    int b = p0 >> 14, rem = p0 & 16383, y = rem >> 7, x0 = rem & 127;
    int wv = t >> 6, ln = t & 63;

    f32x4 acc0 = {0.f, 0.f, 0.f, 0.f};
    f32x4 acc1 = {0.f, 0.f, 0.f, 0.f};

    const ushort* xbb = xTb + (size_t)b * 1048576;

    for (int k = 0; k < 9; ++k) {
        // stage weights: 32 ch x 64 c
        {
            int ch = t >> 3, c0 = (t & 7) * 8;
            uint4 v = *(const uint4*)&wOffB[(size_t)(k * 32 + ch) * 64 + c0];
            *(uint4*)&wL[ch][c0] = v;
        }
        // stage im2col A: 64 px x 64 c
        int ky = k / 3, kx = k - ky * 3;
        int yy = y + ky - 1;
        bool yok = (unsigned)yy < 128u;
#pragma unroll
        for (int it = 0; it < 2; ++it) {
            int idx = it * 256 + t;
            int px = idx >> 3, c0 = (idx & 7) * 8;
            int xx = x0 + px + kx - 1;
            uint4 v = {0u, 0u, 0u, 0u};
            if (yok && ((unsigned)xx < 128u))
                v = *(const uint4*)&xbb[((size_t)(yy * 128 + xx)) * 64 + c0];
            *(uint4*)&sA[px][c0] = v;
        }
        __syncthreads();
        int m = wv * 16 + (ln & 15);
        int q8 = (ln >> 4) * 8;
        int n = ln & 15;
#pragma unroll
        for (int ks = 0; ks < 2; ++ks) {
            bf16x8 a  = __builtin_bit_cast(bf16x8, *(const uint4*)&sA[m][ks * 32 + q8]);
            bf16x8 b0 = __builtin_bit_cast(bf16x8, *(const uint4*)&wL[n][ks * 32 + q8]);
            bf16x8 b1 = __builtin_bit_cast(bf16x8, *(const uint4*)&wL[16 + n][ks * 32 + q8]);
            acc0 = __builtin_amdgcn_mfma_f32_16x16x32_bf16(a, b0, acc0, 0, 0, 0);
            acc1 = __builtin_amdgcn_mfma_f32_16x16x32_bf16(a, b1, acc1, 0, 0, 0);
        }
        __syncthreads();
    }

    // epilogue: C layout col=lane&15 (ch), row=(lane>>4)*4+r (px)
    int n = ln & 15;
    int pxl = wv * 16 + ((ln >> 4) << 2);
#pragma unroll
    for (int r = 0; r < 4; ++r) {
        int px = pxl + r;
        int sp = (y << 7) + x0 + px;
        {
            float val = acc0[r] + b_off[n];
            float* dst = (n & 1) ? dxp : dyp;
            dst[((b * 9 + (n >> 1)) << 14) + sp] = val;
        }
        int ch = 16 + n;
        float v1 = acc1[r];
        if (ch < 18) {
            float val = v1 + b_off[ch];
            float* dst = (ch & 1) ? dxp : dyp;
            dst[((b * 9 + (ch >> 1)) << 14) + sp] = val;
        } else if (ch < 27) {
            float val = v1 + b_mask[ch - 18];
            mkp[((b * 9 + (ch - 18)) << 14) + sp] = 1.f / (1.f + __expf(-val));
        }
    }
}

// ---------------- main: bilinear sample + MFMA contraction ----------------
// block: 64 px, M=64 (4 waves x 16), N=64 (4 tiles), K=576 (9 taps x 64c)
__global__ __launch_bounds__(256) void dcn_main_kernel(
    const ushort* __restrict__ xTb, const ushort* __restrict__ wMainB,
    const float* __restrict__ dyp, const float* __restrict__ dxp, const float* __restrict__ mkp,
    const float* __restrict__ b_dcn, float* __restrict__ out)
{
    __shared__ union {
        struct { ushort A[64][72]; ushort W[64][72]; float off[3][9][64]; } s;
        float ep[64][65];
    } sm;

    int t = threadIdx.x;
    int p0 = blockIdx.x * 64;
    int b = p0 >> 14, rem = p0 & 16383, y = rem >> 7, x0 = rem & 127;
    int wv = t >> 6, ln = t & 63;

    // stage dy/dx/mask for this block's 64 px
    for (int i = t; i < 1728; i += 256) {
        int arr = i / 576;
        int r = i - arr * 576;
        int k = r >> 6, px = r & 63;
        const float* src = (arr == 0) ? dyp : (arr == 1 ? dxp : mkp);
        sm.s.off[arr][k][px] = src[((b * 9 + k) << 14) + (y << 7) + x0 + px];
    }
    __syncthreads();

    f32x4 acc[4];
#pragma unroll
    for (int i = 0; i < 4; ++i) acc[i] = f32x4{0.f, 0.f, 0.f, 0.f};

    int px_s = t & 63;     // sampling: this thread's pixel
    int cq = t >> 6;       // sampling: channel quarter (16 c)
    const ushort* xbb = xTb + (size_t)b * 1048576;

    for (int k = 0; k < 9; ++k) {
        // stage weights [k][o][c] -> wL
#pragma unroll
        for (int it = 0; it < 2; ++it) {
            int idx = it * 256 + t;
            int o = idx >> 3, c0 = (idx & 7) * 8;
            *(uint4*)&sm.s.W[o][c0] = *(const uint4*)&wMainB[(size_t)((k * 64 + o) * 64) + c0];
        }
        // bilinear sample 16 channels for (px_s, tap k)
        int ky = k / 3, kx = k - ky * 3;
        float dyv = sm.s.off[0][k][px_s];
        float dxv = sm.s.off[1][k][px_s];
        float mkv = sm.s.off[2][k][px_s];
        float py  = (float)(y + ky - 1) + dyv;
        float pxf = (float)(x0 + px_s + kx - 1) + dxv;
        float y0f = floorf(py), x0f = floorf(pxf);
        float wy1 = py - y0f, wy0 = 1.f - wy1;
        float wx1 = pxf - x0f, wx0 = 1.f - wx1;
        bool vy0 = (y0f >= 0.f) && (y0f <= 127.f);
        bool vy1 = (y0f >= -1.f) && (y0f <= 126.f);
        bool vx0 = (x0f >= 0.f) && (x0f <= 127.f);
        bool vx1 = (x0f >= -1.f) && (x0f <= 126.f);
        float w00 = (vy0 && vx0) ? wy0 * wx0 * mkv : 0.f;
        float w01 = (vy0 && vx1) ? wy0 * wx1 * mkv : 0.f;
        float w10 = (vy1 && vx0) ? wy1 * wx0 * mkv : 0.f;
        float w11 = (vy1 && vx1) ? wy1 * wx1 * mkv : 0.f;
        int yi0 = (int)y0f, xi0 = (int)x0f;
        int y0c = min(max(yi0, 0), 127),     y1c = min(max(yi0 + 1, 0), 127);
        int x0c = min(max(xi0, 0), 127),     x1c = min(max(xi0 + 1, 0), 127);
        const ushort* p00 = xbb + (size_t)((y0c << 7) + x0c) * 64 + cq * 16;
        const ushort* p01 = xbb + (size_t)((y0c << 7) + x1c) * 64 + cq * 16;
        const ushort* p10 = xbb + (size_t)((y1c << 7) + x0c) * 64 + cq * 16;
        const ushort* p11 = xbb + (size_t)((y1c << 7) + x1c) * 64 + cq * 16;
        union U8 { uint4 q[2]; uint u[8]; } v00, v01, v10, v11;
        v00.q[0] = *(const uint4*)p00;       v00.q[1] = *(const uint4*)(p00 + 8);
        v01.q[0] = *(const uint4*)p01;       v01.q[1] = *(const uint4*)(p01 + 8);
        v10.q[0] = *(const uint4*)p10;       v10.q[1] = *(const uint4*)(p10 + 8);
        v11.q[0] = *(const uint4*)p11;       v11.q[1] = *(const uint4*)(p11 + 8);
        union { uint u[8]; uint4 q[2]; } wr;
#pragma unroll
        for (int j = 0; j < 8; ++j) {
            float f00l = __uint_as_float(v00.u[j] << 16);
            float f00h = __uint_as_float(v00.u[j] & 0xffff0000u);
            float f01l = __uint_as_float(v01.u[j] << 16);
            float f01h = __uint_as_float(v01.u[j] & 0xffff0000u);
            float f10l = __uint_as_float(v10.u[j] << 16);
            float f10h = __uint_as_float(v10.u[j] & 0xffff0000u);
            float f11l = __uint_as_float(v11.u[j] << 16);
            float f11h = __uint_as_float(v11.u[j] & 0xffff0000u);
            float vl = w00 * f00l;
            vl = fmaf(w01, f01l, vl); vl = fmaf(w10, f10l, vl); vl = fmaf(w11, f11l, vl);
            float vh = w00 * f00h;
            vh = fmaf(w01, f01h, vh); vh = fmaf(w10, f10h, vh); vh = fmaf(w11, f11h, vh);
            wr.u[j] = (f2bf_bits(vh) << 16) | f2bf_bits(vl);
        }
        *(uint4*)&sm.s.A[px_s][cq * 16]     = wr.q[0];
        *(uint4*)&sm.s.A[px_s][cq * 16 + 8] = wr.q[1];
        __syncthreads();

        // MFMA: 2 K-steps x 4 N-tiles
        int m = wv * 16 + (ln & 15);
        int q8 = (ln >> 4) * 8;
        int n = ln & 15;
#pragma unroll
        for (int ks = 0; ks < 2; ++ks) {
            bf16x8 a = __builtin_bit_cast(bf16x8, *(const uint4*)&sm.s.A[m][ks * 32 + q8]);
#pragma unroll
            for (int nt = 0; nt < 4; ++nt) {
                bf16x8 bb = __builtin_bit_cast(bf16x8, *(const uint4*)&sm.s.W[nt * 16 + n][ks * 32 + q8]);
                acc[nt] = __builtin_amdgcn_mfma_f32_16x16x32_bf16(a, bb, acc[nt], 0, 0, 0);
            }
        }
        __syncthreads();
    }

    // epilogue via LDS transpose: acc -> ep[o][px], then coalesced float4 stores
#pragma unroll
    for (int nt = 0; nt < 4; ++nt) {
        int o = nt * 16 + (ln & 15);
        int pxl = wv * 16 + ((ln >> 4) << 2);
#pragma unroll
        for (int r = 0; r < 4; ++r)
            sm.ep[o][pxl + r] = acc[nt][r];
    }
    __syncthreads();
    {
        int o = t >> 2, pxq = (t & 3) * 16;
        float bias = b_dcn[o];
        float* orow = out + ((size_t)(b * 64 + o) << 14) + (y << 7) + x0 + pxq;
#pragma unroll
        for (int i = 0; i < 4; ++i) {
            float4 v;
            v.x = sm.ep[o][pxq + i * 4 + 0] + bias;
            v.y = sm.ep[o][pxq + i * 4 + 1] + bias;
            v.z = sm.ep[o][pxq + i * 4 + 2] + bias;
            v.w = sm.ep[o][pxq + i * 4 + 3] + bias;
            *(float4*)&orow[i * 4] = v;
        }
    }
}

extern "C" void kernel_launch(void* const* d_in, const int* in_sizes, int n_in,
                              void* d_out, int out_size, void* d_ws, size_t ws_size,
                              hipStream_t stream) {
    const float* x      = (const float*)d_in[0];
    const float* w_off  = (const float*)d_in[1];
    const float* b_off  = (const float*)d_in[2];
    const float* w_mask = (const float*)d_in[3];
    const float* b_mask = (const float*)d_in[4];
    const float* w_dcn  = (const float*)d_in[5];
    const float* b_dcn  = (const float*)d_in[6];
    float* out = (float*)d_out;

    const size_t N1 = (size_t)Bt * 9 * HWt;          // 1179648 floats
    float* ws  = (float*)d_ws;
    float* dyp = ws;
    float* dxp = ws + N1;
    float* mkp = ws + 2 * N1;
    ushort* xTb   = (ushort*)(ws + 3 * N1);          // 8.4M bf16
    ushort* wOffB = xTb + (size_t)Bt * HWt * 64;     // 18432
    ushort* wMainB = wOffB + 18432;                  // 36864

    hipLaunchKernelGGL(prep_kernel, dim3(1024 + 216), dim3(256), 0, stream,
                       x, w_off, w_mask, w_dcn, xTb, wOffB, wMainB);
    hipLaunchKernelGGL(offmask_kernel, dim3(2048), dim3(256), 0, stream,
                       xTb, wOffB, b_off, b_mask, dyp, dxp, mkp);
    hipLaunchKernelGGL(dcn_main_kernel, dim3(2048), dim3(256), 0, stream,
                       xTb, wMainB, dyp, dxp, mkp, b_dcn, out);
}